// Round 1
// baseline (653.215 us; speedup 1.0000x reference)
//
#include <hip/hip_runtime.h>

// One thread per window. Layout of samples: [(pixel p)*N + n]*3 + c.
// Consecutive lanes (consecutive n) read contiguous 12B triples -> coalesced.
__global__ __launch_bounds__(256) void spa_kernel(
    const float* __restrict__ s1, const float* __restrict__ s2,
    float* __restrict__ out, int N, float scale) {
  int n = blockIdx.x * blockDim.x + threadIdx.x;

  float D[9];
#pragma unroll
  for (int k = 0; k < 9; ++k) D[k] = 0.f;

  if (n < N) {
    const size_t stride = (size_t)N * 3u;  // floats between pixel slabs
    const float* p1 = s1 + (size_t)n * 3u;
    const float* p2 = s2 + (size_t)n * 3u;
    for (int i = 0; i < 12; ++i) {
      const int pi = (i >> 2) * 3;
      const float* q1 = p1 + (size_t)(i * 12) * stride;
      const float* q2 = p2 + (size_t)(i * 12) * stride;
#pragma unroll
      for (int j = 0; j < 12; ++j) {
        const float* a = q1 + (size_t)j * stride;
        const float* b = q2 + (size_t)j * stride;
        float d = (a[0] + a[1] + a[2]) - (b[0] + b[1] + b[2]);
        D[pi + (j >> 2)] += d;
      }
    }
  }

  // Pooled diff: D currently holds sum over 16 pixels x 3 channels of (s1-s2).
  // true pooled diff = D / 48.
  const float inv48 = 1.0f / 48.0f;
  float P[9];
#pragma unroll
  for (int k = 0; k < 9; ++k) P[k] = D[k] * inv48;

  // 4 directional grads with zero padding, squared-diff sum.
  float e = 0.f;
#pragma unroll
  for (int i = 0; i < 3; ++i) {
#pragma unroll
    for (int j = 0; j < 3; ++j) {
      float c = P[i * 3 + j];
      float l = (j > 0) ? P[i * 3 + j - 1] : 0.f;
      float r = (j < 2) ? P[i * 3 + j + 1] : 0.f;
      float u = (i > 0) ? P[(i - 1) * 3 + j] : 0.f;
      float d = (i < 2) ? P[(i + 1) * 3 + j] : 0.f;
      float dl = c - l, dr = c - r, du = c - u, dd = c - d;
      e += dl * dl + dr * dr + du * du + dd * dd;
    }
  }

  // Block reduction: wave64 shuffle -> LDS -> one atomic per block.
#pragma unroll
  for (int off = 32; off > 0; off >>= 1) e += __shfl_down(e, off, 64);
  __shared__ float sm[4];
  int lane = threadIdx.x & 63;
  int wid = threadIdx.x >> 6;
  if (lane == 0) sm[wid] = e;
  __syncthreads();
  if (threadIdx.x == 0) {
    atomicAdd(out, (sm[0] + sm[1] + sm[2] + sm[3]) * scale);
  }
}

extern "C" void kernel_launch(void* const* d_in, const int* in_sizes, int n_in,
                              void* d_out, int out_size, void* d_ws, size_t ws_size,
                              hipStream_t stream) {
  const float* s1 = (const float*)d_in[0];
  const float* s2 = (const float*)d_in[1];
  float* out = (float*)d_out;
  // in_sizes[0] = 12*12*windows_num*3
  int N = in_sizes[0] / (12 * 12 * 3);
  float scale = 1.0f / (9.0f * (float)N);
  // d_out is poisoned 0xAA before every launch -> zero it (capture-safe).
  hipMemsetAsync(d_out, 0, sizeof(float), stream);
  int blocks = (N + 255) / 256;
  spa_kernel<<<blocks, 256, 0, stream>>>(s1, s2, out, N, scale);
}

// Round 2
// 618.222 us; speedup vs baseline: 1.0566x; 1.0566x over previous
//
#include <hip/hip_runtime.h>

// Layout of samples: [(pixel p)*N + n]*3 + c, p = i*12 + j.
// 4 threads per window (3 rows each), 64 windows per block.
// Consecutive lanes = consecutive windows -> 768B contiguous per pixel slab.
__global__ __launch_bounds__(256) void spa_kernel(
    const float* __restrict__ s1, const float* __restrict__ s2,
    float* __restrict__ out, int N, float scale) {
  const int lane = threadIdx.x & 63;
  const int rg   = threadIdx.x >> 6;         // row group: rows rg*3 .. rg*3+2
  const int win  = blockIdx.x * 64 + lane;

  // rowacc[ii][pc]: sum over the row's 3 channels and 4-col pool groups of (s1-s2)
  float rowacc[3][3];
#pragma unroll
  for (int a = 0; a < 3; ++a)
#pragma unroll
    for (int b = 0; b < 3; ++b) rowacc[a][b] = 0.f;

  if (win < N) {
    const size_t stride = (size_t)N * 3u;    // floats between pixel slabs
    const float* p1 = s1 + (size_t)win * 3u;
    const float* p2 = s2 + (size_t)win * 3u;
#pragma unroll
    for (int ii = 0; ii < 3; ++ii) {
      const int i = rg * 3 + ii;
      const float* q1 = p1 + (size_t)(i * 12) * stride;
      const float* q2 = p2 + (size_t)(i * 12) * stride;
#pragma unroll
      for (int j = 0; j < 12; ++j) {
        const float* a = q1 + (size_t)j * stride;
        const float* b = q2 + (size_t)j * stride;
        float d = (a[0] + a[1] + a[2]) - (b[0] + b[1] + b[2]);
        rowacc[ii][j >> 2] += d;
      }
    }
  }

  // sRow[row][window-in-block][pool col]; lane stride 3 floats -> conflict-free
  __shared__ float sRow[12][64][3];
#pragma unroll
  for (int ii = 0; ii < 3; ++ii) {
    const int i = rg * 3 + ii;
#pragma unroll
    for (int c = 0; c < 3; ++c) sRow[i][lane][c] = rowacc[ii][c];
  }
  __syncthreads();

  if (rg == 0) {
    // Pooled diff P = (sum over 4 rows of row partials) / 48
    float P[9];
#pragma unroll
    for (int p = 0; p < 3; ++p)
#pragma unroll
      for (int c = 0; c < 3; ++c) {
        float v = sRow[4 * p][lane][c] + sRow[4 * p + 1][lane][c] +
                  sRow[4 * p + 2][lane][c] + sRow[4 * p + 3][lane][c];
        P[p * 3 + c] = v * (1.0f / 48.0f);
      }

    // 4 directional grads (zero padding), squared sum. win>=N lanes have P=0 -> e=0.
    float e = 0.f;
#pragma unroll
    for (int i = 0; i < 3; ++i) {
#pragma unroll
      for (int j = 0; j < 3; ++j) {
        float c = P[i * 3 + j];
        float l = (j > 0) ? P[i * 3 + j - 1] : 0.f;
        float r = (j < 2) ? P[i * 3 + j + 1] : 0.f;
        float u = (i > 0) ? P[(i - 1) * 3 + j] : 0.f;
        float d = (i < 2) ? P[(i + 1) * 3 + j] : 0.f;
        float dl = c - l, dr = c - r, du = c - u, dd = c - d;
        e += dl * dl + dr * dr + du * du + dd * dd;
      }
    }

    // Reduce over the 64 windows of this block, one atomic per block.
#pragma unroll
    for (int off = 32; off > 0; off >>= 1) e += __shfl_down(e, off, 64);
    if (lane == 0) atomicAdd(out, e * scale);
  }
}

extern "C" void kernel_launch(void* const* d_in, const int* in_sizes, int n_in,
                              void* d_out, int out_size, void* d_ws, size_t ws_size,
                              hipStream_t stream) {
  const float* s1 = (const float*)d_in[0];
  const float* s2 = (const float*)d_in[1];
  float* out = (float*)d_out;
  int N = in_sizes[0] / (12 * 12 * 3);
  float scale = 1.0f / (9.0f * (float)N);
  hipMemsetAsync(d_out, 0, sizeof(float), stream);
  int blocks = (N + 63) / 64;
  spa_kernel<<<blocks, 256, 0, stream>>>(s1, s2, out, N, scale);
}